// Round 13
// baseline (336.514 us; speedup 1.0000x reference)
//
#include <hip/hip_runtime.h>

#define IN_DIM 40
#define HID 64
#define TSTEPS 500
#define NCH 2              // chains per block; 512 blocks -> 2 independent blocks/CU
#define ROWB 192           // chain-row stride: 48 dwords === 16 (mod 32) -> broadcast reads conflict-free
#define SLABP (NCH * ROWB) // 384 B per parity

typedef _Float16 half8 __attribute__((ext_vector_type(8)));
typedef float    f32x4 __attribute__((ext_vector_type(4)));

#define L2E  1.4426950408889634f   // log2(e); weights prescaled so acts use exp2 directly
#define L2E2 2.8853900817779268f   // 2*log2(e)

__device__ __forceinline__ float exp2_fast(float x) {
    return __builtin_amdgcn_exp2f(x);     // v_exp_f32 computes 2^x natively
}

// LDS-visibility barrier: no vmcnt drain (in-flight global prefetch survives).
__device__ __forceinline__ void block_sync_lds() {
    asm volatile("s_waitcnt lgkmcnt(0)" ::: "memory");
    __builtin_amdgcn_s_barrier();
    asm volatile("" ::: "memory");
}

// MFMA recurrence, 2 chains/block, 2 FAT waves/block (8 m-tiles each), 512 blocks
// (2 blocks/CU). Per-CU MFMA issue unchanged vs 4-wave version, per-CU VALU ~halved:
// all 64 lanes are cell owners (no wasted act lanes), per-wave overhead paid 4x not 8x.
// W rows gate-interleaved + exp2-prescaled. h stored once per chain (192B rows),
// replicated via broadcast-read addressing. One lgkm-only barrier per step.
__global__ __launch_bounds__(128, 1)
void lstm_mfma(const float* __restrict__ x,
               const float* __restrict__ W_ih,
               const float* __restrict__ W_hh,
               const float* __restrict__ b_ih,
               const float* __restrict__ b_hh,
               const float* __restrict__ fc1_w,
               const float* __restrict__ fc1_b,
               const float* __restrict__ fc2_w,
               const float* __restrict__ fc2_b,
               float* __restrict__ out)
{
    const int tid = threadIdx.x;
    const int w   = tid >> 6;        // wave id 0/1: m-tiles 8w..8w+7 (units 32w..32w+31)
    const int l   = tid & 63;
    const int lr  = l & 15;          // B/D column
    const int lg  = l >> 4;          // k-group / D-row group
    const int ch  = lr & 1;          // this lane's chain
    const int jj  = lr >> 1;         // owned m-tile within wave (0..7) — ALL lanes own
    const int blk = blockIdx.x;

    __shared__ __align__(16) unsigned char slab[2 * SLABP];   // 768 B, parity dbuf
    __shared__ float h32[NCH][HID];
    __shared__ float rl [NCH][HID];

    // ---- zero slab parity 0 (h0 = 0): 384 B = 24 x uint4 ----
    if (tid < SLABP / 16) reinterpret_cast<uint4*>(slab)[tid] = uint4{0, 0, 0, 0};

    // ---- persistent A-fragments: 8 tiles x 4 k-tiles (gate-interleaved, prescaled) ----
    half8 wfrag[8][4];               // 128 VGPRs
    #pragma unroll
    for (int j = 0; j < 8; ++j) {
        const int jt   = 8 * w + j;
        const int unit = 4 * jt + (lr >> 2);
        const int gate = lr & 3;
        const int row  = gate * HID + unit;
        const float sc = (gate == 2) ? L2E2 : L2E;   // tanh rows get 2log2e
        #pragma unroll
        for (int kt = 0; kt < 4; ++kt) {
            const int k0 = kt * 32 + lg * 8;
            float v[8];
            if (k0 < 64) {
                const float4* p = reinterpret_cast<const float4*>(W_hh + (size_t)row * HID + k0);
                float4 q0 = p[0], q1 = p[1];
                v[0]=q0.x; v[1]=q0.y; v[2]=q0.z; v[3]=q0.w;
                v[4]=q1.x; v[5]=q1.y; v[6]=q1.z; v[7]=q1.w;
            } else if (k0 < 104) {
                const float4* p = reinterpret_cast<const float4*>(W_ih + (size_t)row * IN_DIM + (k0 - 64));
                float4 q0 = p[0], q1 = p[1];
                v[0]=q0.x; v[1]=q0.y; v[2]=q0.z; v[3]=q0.w;
                v[4]=q1.x; v[5]=q1.y; v[6]=q1.z; v[7]=q1.w;
            } else {
                #pragma unroll
                for (int e = 0; e < 8; ++e) v[e] = 0.0f;
            }
            half8 hv;
            #pragma unroll
            for (int e = 0; e < 8; ++e) hv[e] = (_Float16)(v[e] * sc);
            wfrag[j][kt] = hv;
        }
    }

    // ---- per-lane bias for the single owned cell (added post-select) ----
    const int uown = 32 * w + 4 * jj + lg;   // unit of this lane's cell
    const f32x4 biasown = {
        (b_ih[0 * HID + uown] + b_hh[0 * HID + uown]) * L2E,
        (b_ih[1 * HID + uown] + b_hh[1 * HID + uown]) * L2E,
        (b_ih[2 * HID + uown] + b_hh[2 * HID + uown]) * L2E2,
        (b_ih[3 * HID + uown] + b_hh[3 * HID + uown]) * L2E };

    // ---- per-lane x addresses: chain ch; kt=2 elems lg*8..+7, kt=3 elems 32..39 ----
    const float* xrow = x + ((size_t)(blk * NCH + ch) * TSTEPS) * IN_DIM;
    const float* xg2  = xrow + lg * 8;
    const float* xg3  = xrow + 32;      // kt=3: A-rows beyond k=40 are zero (pad)

    // single x register buffer: holds x_t at the top of step t
    float4 xb0 = *reinterpret_cast<const float4*>(xg2);
    float4 xb1 = *reinterpret_cast<const float4*>(xg2 + 4);
    float4 xb2 = *reinterpret_cast<const float4*>(xg3);
    float4 xb3 = *reinterpret_cast<const float4*>(xg3 + 4);

    __syncthreads();   // one-time full drain (slab zero + x_0 visible)

    float cs = 0.0f;   // ONE cell per lane: (chain ch, unit uown)

    auto step = [&](int t, int par, bool lastt) {
        // 1. issue h B-frag reads (broadcast, conflict-free via 192B rows)
        const unsigned char* sb = slab + par * SLABP + ch * ROWB;
        uint4 q0 = *reinterpret_cast<const uint4*>(sb + lg * 16);
        uint4 q1 = *reinterpret_cast<const uint4*>(sb + 64 + lg * 16);
        // 2. under the ds_read shadow: convert x_t, compute x-part for all 8 tiles
        half8 xf2 = { (_Float16)xb0.x, (_Float16)xb0.y, (_Float16)xb0.z, (_Float16)xb0.w,
                      (_Float16)xb1.x, (_Float16)xb1.y, (_Float16)xb1.z, (_Float16)xb1.w };
        half8 xf3 = { (_Float16)xb2.x, (_Float16)xb2.y, (_Float16)xb2.z, (_Float16)xb2.w,
                      (_Float16)xb3.x, (_Float16)xb3.y, (_Float16)xb3.z, (_Float16)xb3.w };
        f32x4 xacc[8];
        #pragma unroll
        for (int j = 0; j < 8; ++j) {
            f32x4 a = f32x4{0.0f, 0.0f, 0.0f, 0.0f};
            a = __builtin_amdgcn_mfma_f32_16x16x32_f16(wfrag[j][2], xf2, a, 0, 0, 0);
            a = __builtin_amdgcn_mfma_f32_16x16x32_f16(wfrag[j][3], xf3, a, 0, 0, 0);
            xacc[j] = a;
        }
        // 3. x_t consumed -> issue x_{t+1} prefetch into the same buffer
        //    (in flight across the lgkm-only barrier; waited ~a full step later)
        {
            const size_t toff = (size_t)((t + 1 < TSTEPS) ? t + 1 : TSTEPS - 1) * IN_DIM;
            xb0 = *reinterpret_cast<const float4*>(xg2 + toff);
            xb1 = *reinterpret_cast<const float4*>(xg2 + toff + 4);
            xb2 = *reinterpret_cast<const float4*>(xg3 + toff);
            xb3 = *reinterpret_cast<const float4*>(xg3 + toff + 4);
        }
        // 4. h MFMAs (depth-2 on top of xacc) + incremental owner select
        half8 bf0 = __builtin_bit_cast(half8, q0);   // compiler inserts lgkm wait here
        half8 bf1 = __builtin_bit_cast(half8, q1);
        f32x4 zs;
        #pragma unroll
        for (int j = 0; j < 8; ++j) {
            f32x4 a = __builtin_amdgcn_mfma_f32_16x16x32_f16(wfrag[j][0], bf0, xacc[j], 0, 0, 0);
            a = __builtin_amdgcn_mfma_f32_16x16x32_f16(wfrag[j][1], bf1, a, 0, 0, 0);
            if (j == 0) {
                zs = a;
            } else {
                const bool m = (jj == j);
                zs[0] = m ? a[0] : zs[0];
                zs[1] = m ? a[1] : zs[1];
                zs[2] = m ? a[2] : zs[2];
                zs[3] = m ? a[3] : zs[3];
            }
        }
        // 5. bias + exp2-direct activations (z prescaled by log2e / 2log2e)
        float z0 = zs[0] + biasown[0];
        float z1 = zs[1] + biasown[1];
        float z2 = zs[2] + biasown[2];
        float z3 = zs[3] + biasown[3];
        float iv = __builtin_amdgcn_rcpf(1.0f + exp2_fast(-z0));
        float fv = __builtin_amdgcn_rcpf(1.0f + exp2_fast(-z1));
        float ov = __builtin_amdgcn_rcpf(1.0f + exp2_fast(-z3));
        float e2 = exp2_fast(-fabsf(z2));
        float gv = copysignf((1.0f - e2) * __builtin_amdgcn_rcpf(1.0f + e2), z2);
        cs = fmaf(fv, cs, iv * gv);
        float ec = exp2_fast(-fabsf(cs * L2E2));
        float h  = ov * copysignf((1.0f - ec) * __builtin_amdgcn_rcpf(1.0f + ec), cs);
        // 6. every lane publishes its cell's h (2-way bank aliasing = free)
        if (lastt) {
            h32[ch][uown] = h;
        } else {
            unsigned char* db = slab + (par ^ 1) * SLABP + ch * ROWB + uown * 2;
            _Float16 hf = (_Float16)h;
            *reinterpret_cast<unsigned short*>(db) = __builtin_bit_cast(unsigned short, hf);
        }
        // 7. the only per-step barrier (lgkmcnt only; global prefetch stays in flight)
        block_sync_lds();
    };

    #pragma unroll 1
    for (int t = 0; t < TSTEPS; t += 2) {
        step(t,     0, false);
        step(t + 1, 1, t + 1 == TSTEPS - 1);
    }

    // ---- epilogue: fc1 + relu (wave w -> chain w), then fc2 ----
    {
        float acc = fc1_b[l];
        const float4* fwp = reinterpret_cast<const float4*>(fc1_w + (size_t)l * HID);
        #pragma unroll
        for (int q = 0; q < 16; ++q) {
            float4 wv = fwp[q];
            float4 hv = reinterpret_cast<const float4*>(&h32[w][0])[q];
            acc = fmaf(wv.x, hv.x, acc);
            acc = fmaf(wv.y, hv.y, acc);
            acc = fmaf(wv.z, hv.z, acc);
            acc = fmaf(wv.w, hv.w, acc);
        }
        rl[w][l] = fmaxf(acc, 0.0f);
    }
    __syncthreads();
    if (tid < NCH * 2) {
        const int c = tid >> 1;
        const int o = tid & 1;
        float acc = fc2_b[o];
        for (int k = 0; k < HID; ++k)
            acc = fmaf(fc2_w[o * HID + k], rl[c][k], acc);
        out[(size_t)(blk * NCH + c) * 2 + o] = acc;
    }
}

extern "C" void kernel_launch(void* const* d_in, const int* in_sizes, int n_in,
                              void* d_out, int out_size, void* d_ws, size_t ws_size,
                              hipStream_t stream) {
    const float* x     = (const float*)d_in[0];
    const float* W_ih  = (const float*)d_in[1];
    const float* W_hh  = (const float*)d_in[2];
    const float* b_ih  = (const float*)d_in[3];
    const float* b_hh  = (const float*)d_in[4];
    const float* fc1_w = (const float*)d_in[5];
    const float* fc1_b = (const float*)d_in[6];
    const float* fc2_w = (const float*)d_in[7];
    const float* fc2_b = (const float*)d_in[8];
    float* out = (float*)d_out;

    const int B = in_sizes[0] / (TSTEPS * IN_DIM);   // 1024
    lstm_mfma<<<B / NCH, 128, 0, stream>>>(x, W_ih, W_hh, b_ih, b_hh,
                                           fc1_w, fc1_b, fc2_w, fc2_b, out);
}